// Round 5
// baseline (431.124 us; speedup 1.0000x reference)
//
#include <hip/hip_runtime.h>
#include <hip/hip_bf16.h>
#include <math.h>

#define EPSF 1e-5f
#define SCALEF 0.17677669529663687f  // 32^-0.5
#define LOG2E 1.4426950408889634f

typedef unsigned short u16;
typedef unsigned int u32;
typedef __attribute__((ext_vector_type(8))) short bf16x8;
typedef __attribute__((ext_vector_type(4))) float f32x4;

__device__ __forceinline__ float b2f(u16 u) {
    union { unsigned int i; float f; } v; v.i = ((unsigned int)u) << 16; return v.f;
}
__device__ __forceinline__ u16 f2b(float f) {
    union { float f; unsigned int i; } v; v.f = f;
    unsigned int x = v.i;
    return (u16)((x + 0x7fffu + ((x >> 16) & 1u)) >> 16);  // RNE, finite inputs
}
__device__ __forceinline__ float fexp2(float x) {
#if __has_builtin(__builtin_amdgcn_exp2f)
    return __builtin_amdgcn_exp2f(x);
#else
    return exp2f(x);
#endif
}
__device__ __forceinline__ u32 cvtpk_bf16(float lo, float hi) {
    u32 r;
    asm("v_cvt_pk_bf16_f32 %0, %1, %2" : "=v"(r) : "v"(lo), "v"(hi));
    return r;
}

// ---------------- fp32 -> bf16 convert (vectorized x4) ----------------
__global__ void convert_f32_bf16(const float* __restrict__ src, u16* __restrict__ dst, int n4) {
    int i = blockIdx.x * 256 + threadIdx.x;
    if (i >= n4) return;
    float4 v = ((const float4*)src)[i];
    ushort4 o;
    o.x = f2b(v.x); o.y = f2b(v.y); o.z = f2b(v.z); o.w = f2b(v.w);
    ((ushort4*)dst)[i] = o;
}

// ---------------- W_kv row-permute + convert: K-channels first (256), then V (512) ----------------
__global__ void convert_wkv_perm(const float* __restrict__ W, u16* __restrict__ out) {
    int r = blockIdx.x, cl = threadIdx.x;
    int src = (r < 256) ? ((r >> 5) * 96 + (r & 31))
                        : (((r - 256) >> 6) * 96 + 32 + ((r - 256) & 63));
    out[r * 256 + cl] = f2b(W[src * 256 + cl]);
}

// ---------------- subsample gather (bf16 x_b -> bf16 x_sub) ----------------
__global__ void gather_sub_bf16(const u16* __restrict__ xb, u16* __restrict__ xsub, int n8) {
    int i = blockIdx.x * 256 + threadIdx.x;
    if (i >= n8) return;
    int e = i << 3;
    int row = e >> 8;
    int col = e & 255;
    int b = row / 320;
    int t = row - b * 320;
    int n;
    if (t < 256) n = ((t >> 4) << 6) + ((t & 15) << 1);
    else { int tt = t - 256; n = 1024 + ((tt >> 3) << 5) + ((tt & 7) << 1); }
    *(int4*)(xsub + e) = *(const int4*)(xb + ((size_t)(b * 1280 + n)) * 256 + col);
}

// ---------------- GEMM, 1-wave blocks: C[M,N] = A[M,K] * W[N,K]^T, fused BN stats ----------------
// 64 threads = 1 wave computes a 64x64 output tile; NO LDS, NO barriers: A and W fragments are
// loaded directly from global (A rows are block-private; W is L2-resident). Waves are fully
// independent — latency hidden by unrolled in-wave pipelining + high block occupancy.
// XCD swizzle: id&7 -> xcd; within an XCD, N-tile varies fastest so the NT blocks sharing an
// A-panel hit the same L2 (A fetched from HBM once); M-chunks are contiguous per XCD.
// MODE 0: bf16 C. MODE 1: f32 C. MODE 2 (KV, W pre-permuted K-first): N-tiles 0-3 -> K_raw
// (raw bf16, attn's permuted key rows); N-tiles 4-11 -> Vt_raw (raw bf16 transposed
// [c'=h*64+d][81920], 4 tokens per 8B store via cvt_pk).
// Stats: per-channel sum/sumsq of raw fp32 acc -> atomicAdd sums[rep][2][N], rep = m_tile&7.
template<int MODE, int NT, int KC>
__global__ __launch_bounds__(64) void gemm1w(const u16* __restrict__ A, const u16* __restrict__ Bw,
                                             void* __restrict__ Cv, void* __restrict__ C2v,
                                             int N, float* __restrict__ sums) {
    const int lane = threadIdx.x;
    const int quad = lane >> 4, lc = lane & 15;
    const int id = blockIdx.x;
    const int xcd = id & 7;
    const int l = id >> 3;
    const int mchunk = (int)(gridDim.x >> 3) / NT;
    const int m_t = xcd * mchunk + l / NT;
    const int n_t = l % NT;
    const int m0 = m_t * 64, n0 = n_t * 64;

    const u16* Ap = A  + (size_t)(m0 + lc) * KC + quad * 8;
    const u16* Bp = Bw + (size_t)(n0 + lc) * KC + quad * 8;

    f32x4 acc[4][4];
#pragma unroll
    for (int i = 0; i < 4; ++i)
#pragma unroll
        for (int j = 0; j < 4; ++j) acc[i][j] = (f32x4){0.f, 0.f, 0.f, 0.f};

#pragma unroll 2
    for (int k0 = 0; k0 < KC; k0 += 32) {
        bf16x8 af[4], bfr[4];
#pragma unroll
        for (int mi = 0; mi < 4; ++mi) af[mi]  = *(const bf16x8*)(Ap + (size_t)(mi * 16) * KC + k0);
#pragma unroll
        for (int ni = 0; ni < 4; ++ni) bfr[ni] = *(const bf16x8*)(Bp + (size_t)(ni * 16) * KC + k0);
#pragma unroll
        for (int mi = 0; mi < 4; ++mi)
#pragma unroll
            for (int ni = 0; ni < 4; ++ni)
                acc[mi][ni] = __builtin_amdgcn_mfma_f32_16x16x32_bf16(af[mi], bfr[ni], acc[mi][ni], 0, 0, 0);
    }

    // ---- per-channel stats (raw fp32 acc): sum over mi,r then across quads ----
    float ps[4], ps2[4];
#pragma unroll
    for (int ni = 0; ni < 4; ++ni) { ps[ni] = 0.f; ps2[ni] = 0.f; }
#pragma unroll
    for (int mi = 0; mi < 4; ++mi)
#pragma unroll
        for (int ni = 0; ni < 4; ++ni)
#pragma unroll
            for (int r = 0; r < 4; ++r) {
                float v = acc[mi][ni][r];
                ps[ni] += v; ps2[ni] += v * v;
            }
#pragma unroll
    for (int ni = 0; ni < 4; ++ni) {
        ps[ni]  += __shfl_xor(ps[ni], 16);  ps[ni]  += __shfl_xor(ps[ni], 32);
        ps2[ni] += __shfl_xor(ps2[ni], 16); ps2[ni] += __shfl_xor(ps2[ni], 32);
    }
    if (quad == 0) {
        int rep = m_t & 7;
#pragma unroll
        for (int ni = 0; ni < 4; ++ni) {
            int c = n0 + ni * 16 + lc;
            atomicAdd(&sums[(rep * 2 + 0) * N + c], ps[ni]);
            atomicAdd(&sums[(rep * 2 + 1) * N + c], ps2[ni]);
        }
    }

    // ---- C write ----
    if (MODE == 0 || MODE == 1) {
#pragma unroll
        for (int mi = 0; mi < 4; ++mi)
#pragma unroll
            for (int ni = 0; ni < 4; ++ni)
#pragma unroll
                for (int r = 0; r < 4; ++r) {
                    int row = m0 + mi * 16 + quad * 4 + r;
                    int cn  = n0 + ni * 16 + lc;
                    float v = acc[mi][ni][r];
                    if (MODE == 1) ((float*)Cv)[(size_t)row * N + cn] = v;
                    else           ((u16*)Cv)[(size_t)row * N + cn] = f2b(v);
                }
    } else if (n0 < 256) {
        // K-block: raw bf16 at permuted key row [perm-token][256]
        u16* Kr = (u16*)Cv;
#pragma unroll
        for (int mi = 0; mi < 4; ++mi)
#pragma unroll
            for (int r = 0; r < 4; ++r) {
                int t = m0 + mi * 16 + quad * 4 + r;
                int kk = t & 31;
                int pr = (t & ~31) + ((kk & 4) << 2) + ((kk >> 3) << 2) + (kk & 3);
#pragma unroll
                for (int ni = 0; ni < 4; ++ni) {
                    int c = n0 + ni * 16 + lc;
                    Kr[(size_t)pr * 256 + c] = f2b(acc[mi][ni][r]);
                }
            }
    } else {
        // V-block: raw bf16 transposed [c'][81920], 4 consecutive tokens per 8B store
        u16* Vt = (u16*)C2v;
#pragma unroll
        for (int mi = 0; mi < 4; ++mi)
#pragma unroll
            for (int ni = 0; ni < 4; ++ni) {
                int cp = n0 - 256 + ni * 16 + lc;
                int t0 = m0 + mi * 16 + quad * 4;
                uint2 w;
                w.x = cvtpk_bf16(acc[mi][ni][0], acc[mi][ni][1]);
                w.y = cvtpk_bf16(acc[mi][ni][2], acc[mi][ni][3]);
                *(uint2*)(Vt + (size_t)cp * 81920 + t0) = w;
            }
    }
}

// ---------------- fold BN into per-channel affine (sums replicated x8) ----------------
__global__ void finalize_bn(const float* __restrict__ sum2, const float* __restrict__ g,
                            const float* __restrict__ beta, int cols, float inv_n, float scale,
                            float* __restrict__ AB, int kvperm) {
    int c = blockIdx.x * 256 + threadIdx.x;
    if (c >= cols) return;
    float s = 0.f, s2 = 0.f;
#pragma unroll
    for (int r = 0; r < 8; ++r) {
        s  += sum2[(r * 2 + 0) * cols + c];
        s2 += sum2[(r * 2 + 1) * cols + c];
    }
    int src = c;
    if (kvperm) {
        src = (c < 256) ? ((c >> 5) * 96 + (c & 31))
                        : (((c - 256) >> 6) * 96 + 32 + ((c - 256) & 63));
    }
    float m = s * inv_n;
    float var = s2 * inv_n - m * m;
    float a = g[src] * rsqrtf(var + EPSF) * scale;
    AB[c] = a;
    AB[cols + c] = beta[src] * scale - m * a;
}

// ---------------- fused attention v5: raw K/V, affines folded out of the loop ----------------
__global__ __launch_bounds__(256, 2) void attn_kernel5(const u16* __restrict__ Kr, const u16* __restrict__ Vt,
                                                       const u16* __restrict__ q_raw,
                                                       const float* __restrict__ ABq,
                                                       const float* __restrict__ ABkv,
                                                       u16* __restrict__ o_act) {
    const int tid = threadIdx.x;
    const int wave = tid >> 6, lane = tid & 63;
    const int quad = lane >> 4, lc = lane & 15;
    const int h = blockIdx.x, b = blockIdx.y;

    float qa[8], qb[8];
#pragma unroll
    for (int j = 0; j < 8; ++j) {
        int c = h * 32 + quad * 8 + j;
        float ak = ABkv[c];
        qa[j] = ABq[c] * ak;
        qb[j] = ABq[256 + c] * ak;
    }
    bf16x8 qf[5];
#pragma unroll
    for (int j = 0; j < 5; ++j) {
        const u16* qs = q_raw + ((size_t)(b * 320 + j * 64 + wave * 16 + lc)) * 256 + h * 32 + quad * 8;
        union { int4 v; u16 u[8]; } ld; ld.v = *(const int4*)qs;
        union { bf16x8 v; u16 u[8]; } st;
#pragma unroll
        for (int jj = 0; jj < 8; ++jj) st.u[jj] = f2b(b2f(ld.u[jj]) * qa[jj] + qb[jj]);
        qf[j] = st.v;
    }

    const u16* Kp = Kr + (size_t)b * 1280 * 256 + (size_t)lc * 256 + h * 32 + quad * 8;
    const u16* Vp = Vt + ((size_t)(h * 64 + lc)) * 81920 + b * 1280 + quad * 8;

    f32x4 acc[5][4];
#pragma unroll
    for (int j = 0; j < 5; ++j)
#pragma unroll
        for (int i = 0; i < 4; ++i) acc[j][i] = (f32x4){0.f, 0.f, 0.f, 0.f};
    float lsum[5];
#pragma unroll
    for (int j = 0; j < 5; ++j) lsum[j] = 0.f;

    const f32x4 z = (f32x4){0.f, 0.f, 0.f, 0.f};
    for (int kc = 0; kc < 1280; kc += 32) {
        bf16x8 kfA = *(const bf16x8*)(Kp + (size_t)kc * 256);
        bf16x8 kfB = *(const bf16x8*)(Kp + (size_t)(kc + 16) * 256);
        bf16x8 vf0 = *(const bf16x8*)(Vp + kc);
        bf16x8 vf1 = *(const bf16x8*)(Vp + (size_t)16 * 81920 + kc);
        bf16x8 vf2 = *(const bf16x8*)(Vp + (size_t)32 * 81920 + kc);
        bf16x8 vf3 = *(const bf16x8*)(Vp + (size_t)48 * 81920 + kc);
        f32x4 s0[5], s1[5];
#pragma unroll
        for (int j = 0; j < 5; ++j) {
            s0[j] = __builtin_amdgcn_mfma_f32_16x16x32_bf16(kfA, qf[j], z, 0, 0, 0);
            s1[j] = __builtin_amdgcn_mfma_f32_16x16x32_bf16(kfB, qf[j], z, 0, 0, 0);
        }
#pragma unroll
        for (int j = 0; j < 5; ++j) {
            float p0 = fexp2(s0[j][0]);
            float p1 = fexp2(s0[j][1]);
            float p2 = fexp2(s0[j][2]);
            float p3 = fexp2(s0[j][3]);
            float p4 = fexp2(s1[j][0]);
            float p5 = fexp2(s1[j][1]);
            float p6 = fexp2(s1[j][2]);
            float p7 = fexp2(s1[j][3]);
            lsum[j] += ((p0 + p1) + (p2 + p3)) + ((p4 + p5) + (p6 + p7));
            union { u32 w[4]; bf16x8 v; } pf;
            pf.w[0] = cvtpk_bf16(p0, p1);
            pf.w[1] = cvtpk_bf16(p2, p3);
            pf.w[2] = cvtpk_bf16(p4, p5);
            pf.w[3] = cvtpk_bf16(p6, p7);
            acc[j][0] = __builtin_amdgcn_mfma_f32_16x16x32_bf16(vf0, pf.v, acc[j][0], 0, 0, 0);
            acc[j][1] = __builtin_amdgcn_mfma_f32_16x16x32_bf16(vf1, pf.v, acc[j][1], 0, 0, 0);
            acc[j][2] = __builtin_amdgcn_mfma_f32_16x16x32_bf16(vf2, pf.v, acc[j][2], 0, 0, 0);
            acc[j][3] = __builtin_amdgcn_mfma_f32_16x16x32_bf16(vf3, pf.v, acc[j][3], 0, 0, 0);
        }
    }
    float av[16], bv[16];
#pragma unroll
    for (int t = 0; t < 16; ++t) {
        int cv = 256 + h * 64 + (t >> 2) * 16 + quad * 4 + (t & 3);
        av[t] = ABkv[cv];
        bv[t] = ABkv[768 + cv];
    }
#pragma unroll
    for (int j = 0; j < 5; ++j) {
        float l = lsum[j];
        l += __shfl_xor(l, 16);
        l += __shfl_xor(l, 32);
        float inv = 1.f / l;
        int qrow = b * 320 + j * 64 + wave * 16 + lc;
        u16* dst = o_act + (size_t)qrow * 512 + h * 64 + quad * 4;
#pragma unroll
        for (int nt = 0; nt < 4; ++nt) {
            ushort4 st;
#pragma unroll
            for (int r = 0; r < 4; ++r) {
                float o = av[nt * 4 + r] * (acc[j][nt][r] * inv) + bv[nt * 4 + r];
                float hs = o * fminf(fmaxf(o + 3.f, 0.f), 6.f) * (1.f / 6.f);
                ((u16*)&st)[r] = f2b(hs);
            }
            *(ushort4*)(dst + nt * 16) = st;
        }
    }
}

// ---------------- final BN apply -> d_out (fp32) ----------------
__global__ void bn_apply_out(const float* __restrict__ praw, const float* __restrict__ ABp,
                             float* __restrict__ out, int n4) {
    int i = blockIdx.x * 256 + threadIdx.x;
    if (i >= n4) return;
    int e = i << 2;
    int c = e & 511;
    float4 v = ((const float4*)praw)[i];
    float4 o;
    o.x = v.x * ABp[c]     + ABp[512 + c];
    o.y = v.y * ABp[c + 1] + ABp[512 + c + 1];
    o.z = v.z * ABp[c + 2] + ABp[512 + c + 2];
    o.w = v.w * ABp[c + 3] + ABp[512 + c + 3];
    ((float4*)out)[i] = o;
}

// ---------------- launcher ----------------
extern "C" void kernel_launch(void* const* d_in, const int* in_sizes, int n_in,
                              void* d_out, int out_size, void* d_ws, size_t ws_size,
                              hipStream_t stream) {
    const float* x   = (const float*)d_in[0];
    const float* Wkv = (const float*)d_in[1];
    const float* gkv = (const float*)d_in[2];
    const float* bkv = (const float*)d_in[3];
    const float* Wq  = (const float*)d_in[4];
    const float* gq  = (const float*)d_in[5];
    const float* bq  = (const float*)d_in[6];
    const float* Wp  = (const float*)d_in[7];
    const float* gp  = (const float*)d_in[8];
    const float* bp  = (const float*)d_in[9];
    float* out = (float*)d_out;

    char* ws = (char*)d_ws;
    size_t off = 0;
    auto alloc = [&](size_t bytes) -> void* {
        void* p = ws + off;
        off += (bytes + 255) & ~(size_t)255;
        return p;
    };
    // slot1: x_b (dead after gemm_kv/gather) -> p_raw (written by gemm_p after attn)
    void*  slot1  = alloc(81920ull * 256 * 2);                // 41.9 MB
    u16*   x_b    = (u16*)slot1;
    float* p_raw  = (float*)slot1;
    u16*   K_raw  = (u16*)alloc(81920ull * 256 * 2);          // 41.9 MB raw K, permuted rows
    u16*   Vt_raw = (u16*)alloc(512ull * 81920 * 2);          // 83.9 MB raw V^T [h*64+d][81920]
    u16*   q_raw  = (u16*)alloc(20480ull * 256 * 2);          // 10.5 MB
    // slot2: xsub (dead after gemm_q) -> o_act
    void*  slot2  = alloc(20480ull * 512 * 2);                // 21.0 MB
    u16*   xsub_b = (u16*)slot2;
    u16*   o_act  = (u16*)slot2;
    u16*   Wkv_b  = (u16*)alloc(768ull * 256 * 2);
    u16*   Wq_b   = (u16*)alloc(256ull * 256 * 2);
    u16*   Wp_b   = (u16*)alloc(512ull * 512 * 2);
    float* sums_kv = (float*)alloc(8 * 2 * 768 * sizeof(float));
    float* sums_q  = (float*)alloc(8 * 2 * 256 * sizeof(float));
    float* sums_p  = (float*)alloc(8 * 2 * 512 * sizeof(float));
    float* ABkv = (float*)alloc(1536 * sizeof(float));
    float* ABq  = (float*)alloc(512 * sizeof(float));
    float* ABp  = (float*)alloc(1024 * sizeof(float));

    dim3 blk(256);
    hipMemsetAsync(sums_kv, 0, 8 * 2 * (768 + 256 + 512) * sizeof(float), stream);

    convert_f32_bf16<<<20480, blk, 0, stream>>>(x,   x_b,   5242880);
    convert_wkv_perm<<<768,   blk, 0, stream>>>(Wkv, Wkv_b);
    convert_f32_bf16<<<64,    blk, 0, stream>>>(Wq,  Wq_b,  16384);
    convert_f32_bf16<<<256,   blk, 0, stream>>>(Wp,  Wp_b,  65536);
    gather_sub_bf16<<<2560,   blk, 0, stream>>>(x_b, xsub_b, 655360);

    // 1-wave GEMMs: grid = (M/64) * NT blocks of 64 threads, XCD-swizzled in-kernel
    gemm1w<2, 12, 256><<<15360, 64, 0, stream>>>(x_b,    Wkv_b, K_raw, Vt_raw, 768, sums_kv);
    gemm1w<0, 4,  256><<<1280,  64, 0, stream>>>(xsub_b, Wq_b,  q_raw, nullptr, 256, sums_q);

    finalize_bn<<<3, blk, 0, stream>>>(sums_kv, gkv, bkv, 768, 1.f / 81920.f, 1.f, ABkv, 1);
    finalize_bn<<<1, blk, 0, stream>>>(sums_q,  gq,  bq,  256, 1.f / 20480.f, SCALEF * LOG2E, ABq, 0);

    attn_kernel5<<<dim3(8, 64), blk, 0, stream>>>(K_raw, Vt_raw, q_raw, ABq, ABkv, o_act);

    gemm1w<1, 8, 512><<<2560, 64, 0, stream>>>(o_act, Wp_b, p_raw, nullptr, 512, sums_p);
    finalize_bn<<<2, blk, 0, stream>>>(sums_p, gp, bp, 512, 1.f / 20480.f, 1.f, ABp, 0);

    bn_apply_out<<<10240, blk, 0, stream>>>(p_raw, ABp, out, 2621440);
}

// Round 6
// 380.381 us; speedup vs baseline: 1.1334x; 1.1334x over previous
//
#include <hip/hip_runtime.h>
#include <hip/hip_bf16.h>
#include <math.h>

#define EPSF 1e-5f
#define SCALEF 0.17677669529663687f  // 32^-0.5
#define LOG2E 1.4426950408889634f

typedef unsigned short u16;
typedef unsigned int u32;
typedef __attribute__((ext_vector_type(8))) short bf16x8;
typedef __attribute__((ext_vector_type(4))) float f32x4;

__device__ __forceinline__ float b2f(u16 u) {
    union { unsigned int i; float f; } v; v.i = ((unsigned int)u) << 16; return v.f;
}
__device__ __forceinline__ u16 f2b(float f) {
    union { float f; unsigned int i; } v; v.f = f;
    unsigned int x = v.i;
    return (u16)((x + 0x7fffu + ((x >> 16) & 1u)) >> 16);  // RNE, finite inputs
}
__device__ __forceinline__ float fexp2(float x) {
#if __has_builtin(__builtin_amdgcn_exp2f)
    return __builtin_amdgcn_exp2f(x);
#else
    return exp2f(x);
#endif
}
__device__ __forceinline__ u32 cvtpk_bf16(float lo, float hi) {
    u32 r;
    asm("v_cvt_pk_bf16_f32 %0, %1, %2" : "=v"(r) : "v"(lo), "v"(hi));
    return r;
}
// async global->LDS, 16B per lane; LDS dest is wave-uniform base + lane*16
__device__ __forceinline__ void gload_lds16(const u16* __restrict__ g, u16* l) {
    __builtin_amdgcn_global_load_lds(
        (const __attribute__((address_space(1))) void*)g,
        (__attribute__((address_space(3))) void*)l, 16, 0, 0);
}

// ---------------- fp32 -> bf16 convert (vectorized x4) ----------------
__global__ void convert_f32_bf16(const float* __restrict__ src, u16* __restrict__ dst, int n4) {
    int i = blockIdx.x * 256 + threadIdx.x;
    if (i >= n4) return;
    float4 v = ((const float4*)src)[i];
    ushort4 o;
    o.x = f2b(v.x); o.y = f2b(v.y); o.z = f2b(v.z); o.w = f2b(v.w);
    ((ushort4*)dst)[i] = o;
}

// ---------------- W_kv row-permute + convert: K-channels first (256), then V (512) ----------------
__global__ void convert_wkv_perm(const float* __restrict__ W, u16* __restrict__ out) {
    int r = blockIdx.x, cl = threadIdx.x;
    int src = (r < 256) ? ((r >> 5) * 96 + (r & 31))
                        : (((r - 256) >> 6) * 96 + 32 + ((r - 256) & 63));
    out[r * 256 + cl] = f2b(W[src * 256 + cl]);
}

// ---------------- subsample gather (bf16 x_b -> bf16 x_sub) ----------------
__global__ void gather_sub_bf16(const u16* __restrict__ xb, u16* __restrict__ xsub, int n8) {
    int i = blockIdx.x * 256 + threadIdx.x;
    if (i >= n8) return;
    int e = i << 3;
    int row = e >> 8;
    int col = e & 255;
    int b = row / 320;
    int t = row - b * 320;
    int n;
    if (t < 256) n = ((t >> 4) << 6) + ((t & 15) << 1);
    else { int tt = t - 256; n = 1024 + ((tt >> 3) << 5) + ((tt & 7) << 1); }
    *(int4*)(xsub + e) = *(const int4*)(xb + ((size_t)(b * 1280 + n)) * 256 + col);
}

// ---------------- GEMM, A-in-LDS-once: C[M,N] = A[M,K] * W[N,K]^T, fused BN stats ----------------
// block 256 = 4 waves (2x2), tile 128x128. Per 256-wide K-chunk: stage the ENTIRE 128x256 A-panel
// (64 KB) into LDS via 64 global_load_lds (deep MLP), ONE vmcnt(0)+barrier, then 8 K-steps of
// straight-line compute with NO barriers: A-frags from swizzled LDS (2-way conflicts = free),
// B-frags direct from global (W panel is L2-resident; compiler prefetches across K-steps freely).
// LDS granule swizzle: slot(row,g) holds logical granule g^(row&7) — staged by pre-swizzling the
// per-lane GLOBAL source column (LDS dest stays linear), read back with the same XOR.
// XCD swizzle (FETCH 125->22 MB measured): id&7 -> xcd, contiguous M-chunk per XCD, N fastest.
// MODE 0: bf16 C. MODE 1: f32 C. MODE 2 (KV, W pre-permuted K-first): n0<256 -> K_raw (attn's
// permuted key rows); else Vt_raw transposed [c'][81920] via cvt_pk (8B stores).
// Stats: per-wave shfl reduce, quad0 atomics into sums[rep][2][N], rep = m_t&7.
template<int MODE, int NT, int KC>
__global__ __launch_bounds__(256) void gemm_ls(const u16* __restrict__ A, const u16* __restrict__ Bw,
                                               void* __restrict__ Cv, void* __restrict__ C2v,
                                               int N, float* __restrict__ sums) {
    __shared__ u16 As[128 * 256];   // 64 KB
    const int tid = threadIdx.x;
    const int wave = tid >> 6, lane = tid & 63;
    const int quad = lane >> 4, lc = lane & 15;
    const int wr = wave >> 1, wc = wave & 1;
    const int id = blockIdx.x;
    const int xcd = id & 7, l = id >> 3;
    const int mchunk = ((int)gridDim.x >> 3) / NT;
    const int m_t = xcd * mchunk + l / NT;
    const int n_t = l - (l / NT) * NT;
    const int m0 = m_t * 128, n0 = n_t * 128;

    const int r_in = lane >> 5;       // staging: row parity within 1KB instr
    const int g_l  = lane & 31;       // staging: LDS granule slot
    const u16* Bp = Bw + (size_t)(n0 + wc * 64 + lc) * KC + quad * 8;

    f32x4 acc[4][4];
#pragma unroll
    for (int i = 0; i < 4; ++i)
#pragma unroll
        for (int j = 0; j < 4; ++j) acc[i][j] = (f32x4){0.f, 0.f, 0.f, 0.f};

    for (int kb = 0; kb < KC; kb += 256) {
        if (kb) __syncthreads();      // WAR: all waves done reading previous chunk
        // stage: wave w covers rows [32w, 32w+32); instr s = rows 32w+2s..+1 (1 KB linear dest).
        // lane: row = 32w+2s+(lane>>5), slot g_l -> logical granule g_l^(row&7) -> global col.
#pragma unroll
        for (int s = 0; s < 16; ++s) {
            int Rb = wave * 32 + s * 2;
            int R  = Rb + r_in;
            int col = ((g_l ^ (R & 7)) << 3) + kb;
            gload_lds16(A + (size_t)(m0 + R) * KC + col, &As[Rb * 256]);
        }
        asm volatile("s_waitcnt vmcnt(0)" ::: "memory");
        __syncthreads();
        // compute: 8 K-steps, zero barriers
#pragma unroll
        for (int t = 0; t < 8; ++t) {
            bf16x8 af[4], bfr[4];
#pragma unroll
            for (int mi = 0; mi < 4; ++mi) {
                int R = wr * 64 + mi * 16 + lc;
                int g = (t * 4 + quad) ^ (R & 7);
                af[mi] = *(const bf16x8*)&As[R * 256 + g * 8];
            }
#pragma unroll
            for (int ni = 0; ni < 4; ++ni)
                bfr[ni] = *(const bf16x8*)(Bp + (size_t)(ni * 16) * KC + kb + t * 32);
#pragma unroll
            for (int mi = 0; mi < 4; ++mi)
#pragma unroll
                for (int ni = 0; ni < 4; ++ni)
                    acc[mi][ni] = __builtin_amdgcn_mfma_f32_16x16x32_bf16(af[mi], bfr[ni], acc[mi][ni], 0, 0, 0);
        }
    }

    // ---- per-channel stats (raw fp32 acc) ----
    float ps[4], ps2[4];
#pragma unroll
    for (int ni = 0; ni < 4; ++ni) { ps[ni] = 0.f; ps2[ni] = 0.f; }
#pragma unroll
    for (int mi = 0; mi < 4; ++mi)
#pragma unroll
        for (int ni = 0; ni < 4; ++ni)
#pragma unroll
            for (int r = 0; r < 4; ++r) {
                float v = acc[mi][ni][r];
                ps[ni] += v; ps2[ni] += v * v;
            }
#pragma unroll
    for (int ni = 0; ni < 4; ++ni) {
        ps[ni]  += __shfl_xor(ps[ni], 16);  ps[ni]  += __shfl_xor(ps[ni], 32);
        ps2[ni] += __shfl_xor(ps2[ni], 16); ps2[ni] += __shfl_xor(ps2[ni], 32);
    }
    if (quad == 0) {
        int rep = m_t & 7;
#pragma unroll
        for (int ni = 0; ni < 4; ++ni) {
            int c = n0 + wc * 64 + ni * 16 + lc;
            atomicAdd(&sums[(rep * 2 + 0) * N + c], ps[ni]);
            atomicAdd(&sums[(rep * 2 + 1) * N + c], ps2[ni]);
        }
    }

    // ---- C write ----
    if (MODE == 0 || MODE == 1) {
#pragma unroll
        for (int mi = 0; mi < 4; ++mi)
#pragma unroll
            for (int ni = 0; ni < 4; ++ni)
#pragma unroll
                for (int r = 0; r < 4; ++r) {
                    int row = m0 + wr * 64 + mi * 16 + quad * 4 + r;
                    int cn  = n0 + wc * 64 + ni * 16 + lc;
                    float v = acc[mi][ni][r];
                    if (MODE == 1) ((float*)Cv)[(size_t)row * N + cn] = v;
                    else           ((u16*)Cv)[(size_t)row * N + cn] = f2b(v);
                }
    } else if (n0 < 256) {
        // K-block: raw bf16 at permuted key row [perm-token][256]
        u16* Kr = (u16*)Cv;
#pragma unroll
        for (int mi = 0; mi < 4; ++mi)
#pragma unroll
            for (int r = 0; r < 4; ++r) {
                int t = m0 + wr * 64 + mi * 16 + quad * 4 + r;
                int kk = t & 31;
                int pr = (t & ~31) + ((kk & 4) << 2) + ((kk >> 3) << 2) + (kk & 3);
#pragma unroll
                for (int ni = 0; ni < 4; ++ni) {
                    int c = n0 + wc * 64 + ni * 16 + lc;
                    Kr[(size_t)pr * 256 + c] = f2b(acc[mi][ni][r]);
                }
            }
    } else {
        // V-block: raw bf16 transposed [c'][81920], 4 consecutive tokens per 8B store
        u16* Vt = (u16*)C2v;
#pragma unroll
        for (int mi = 0; mi < 4; ++mi)
#pragma unroll
            for (int ni = 0; ni < 4; ++ni) {
                int cp = n0 - 256 + wc * 64 + ni * 16 + lc;
                int t0 = m0 + wr * 64 + mi * 16 + quad * 4;
                uint2 w;
                w.x = cvtpk_bf16(acc[mi][ni][0], acc[mi][ni][1]);
                w.y = cvtpk_bf16(acc[mi][ni][2], acc[mi][ni][3]);
                *(uint2*)(Vt + (size_t)cp * 81920 + t0) = w;
            }
    }
}

// ---------------- fold BN into per-channel affine (sums replicated x8) ----------------
__global__ void finalize_bn(const float* __restrict__ sum2, const float* __restrict__ g,
                            const float* __restrict__ beta, int cols, float inv_n, float scale,
                            float* __restrict__ AB, int kvperm) {
    int c = blockIdx.x * 256 + threadIdx.x;
    if (c >= cols) return;
    float s = 0.f, s2 = 0.f;
#pragma unroll
    for (int r = 0; r < 8; ++r) {
        s  += sum2[(r * 2 + 0) * cols + c];
        s2 += sum2[(r * 2 + 1) * cols + c];
    }
    int src = c;
    if (kvperm) {
        src = (c < 256) ? ((c >> 5) * 96 + (c & 31))
                        : (((c - 256) >> 6) * 96 + 32 + ((c - 256) & 63));
    }
    float m = s * inv_n;
    float var = s2 * inv_n - m * m;
    float a = g[src] * rsqrtf(var + EPSF) * scale;
    AB[c] = a;
    AB[cols + c] = beta[src] * scale - m * a;
}

// ---------------- fused attention v5: raw K/V, affines folded out of the loop ----------------
__global__ __launch_bounds__(256, 2) void attn_kernel5(const u16* __restrict__ Kr, const u16* __restrict__ Vt,
                                                       const u16* __restrict__ q_raw,
                                                       const float* __restrict__ ABq,
                                                       const float* __restrict__ ABkv,
                                                       u16* __restrict__ o_act) {
    const int tid = threadIdx.x;
    const int wave = tid >> 6, lane = tid & 63;
    const int quad = lane >> 4, lc = lane & 15;
    const int h = blockIdx.x, b = blockIdx.y;

    float qa[8], qb[8];
#pragma unroll
    for (int j = 0; j < 8; ++j) {
        int c = h * 32 + quad * 8 + j;
        float ak = ABkv[c];
        qa[j] = ABq[c] * ak;
        qb[j] = ABq[256 + c] * ak;
    }
    bf16x8 qf[5];
#pragma unroll
    for (int j = 0; j < 5; ++j) {
        const u16* qs = q_raw + ((size_t)(b * 320 + j * 64 + wave * 16 + lc)) * 256 + h * 32 + quad * 8;
        union { int4 v; u16 u[8]; } ld; ld.v = *(const int4*)qs;
        union { bf16x8 v; u16 u[8]; } st;
#pragma unroll
        for (int jj = 0; jj < 8; ++jj) st.u[jj] = f2b(b2f(ld.u[jj]) * qa[jj] + qb[jj]);
        qf[j] = st.v;
    }

    const u16* Kp = Kr + (size_t)b * 1280 * 256 + (size_t)lc * 256 + h * 32 + quad * 8;
    const u16* Vp = Vt + ((size_t)(h * 64 + lc)) * 81920 + b * 1280 + quad * 8;

    f32x4 acc[5][4];
#pragma unroll
    for (int j = 0; j < 5; ++j)
#pragma unroll
        for (int i = 0; i < 4; ++i) acc[j][i] = (f32x4){0.f, 0.f, 0.f, 0.f};
    float lsum[5];
#pragma unroll
    for (int j = 0; j < 5; ++j) lsum[j] = 0.f;

    const f32x4 z = (f32x4){0.f, 0.f, 0.f, 0.f};
    for (int kc = 0; kc < 1280; kc += 32) {
        bf16x8 kfA = *(const bf16x8*)(Kp + (size_t)kc * 256);
        bf16x8 kfB = *(const bf16x8*)(Kp + (size_t)(kc + 16) * 256);
        bf16x8 vf0 = *(const bf16x8*)(Vp + kc);
        bf16x8 vf1 = *(const bf16x8*)(Vp + (size_t)16 * 81920 + kc);
        bf16x8 vf2 = *(const bf16x8*)(Vp + (size_t)32 * 81920 + kc);
        bf16x8 vf3 = *(const bf16x8*)(Vp + (size_t)48 * 81920 + kc);
        f32x4 s0[5], s1[5];
#pragma unroll
        for (int j = 0; j < 5; ++j) {
            s0[j] = __builtin_amdgcn_mfma_f32_16x16x32_bf16(kfA, qf[j], z, 0, 0, 0);
            s1[j] = __builtin_amdgcn_mfma_f32_16x16x32_bf16(kfB, qf[j], z, 0, 0, 0);
        }
#pragma unroll
        for (int j = 0; j < 5; ++j) {
            float p0 = fexp2(s0[j][0]);
            float p1 = fexp2(s0[j][1]);
            float p2 = fexp2(s0[j][2]);
            float p3 = fexp2(s0[j][3]);
            float p4 = fexp2(s1[j][0]);
            float p5 = fexp2(s1[j][1]);
            float p6 = fexp2(s1[j][2]);
            float p7 = fexp2(s1[j][3]);
            lsum[j] += ((p0 + p1) + (p2 + p3)) + ((p4 + p5) + (p6 + p7));
            union { u32 w[4]; bf16x8 v; } pf;
            pf.w[0] = cvtpk_bf16(p0, p1);
            pf.w[1] = cvtpk_bf16(p2, p3);
            pf.w[2] = cvtpk_bf16(p4, p5);
            pf.w[3] = cvtpk_bf16(p6, p7);
            acc[j][0] = __builtin_amdgcn_mfma_f32_16x16x32_bf16(vf0, pf.v, acc[j][0], 0, 0, 0);
            acc[j][1] = __builtin_amdgcn_mfma_f32_16x16x32_bf16(vf1, pf.v, acc[j][1], 0, 0, 0);
            acc[j][2] = __builtin_amdgcn_mfma_f32_16x16x32_bf16(vf2, pf.v, acc[j][2], 0, 0, 0);
            acc[j][3] = __builtin_amdgcn_mfma_f32_16x16x32_bf16(vf3, pf.v, acc[j][3], 0, 0, 0);
        }
    }
    float av[16], bv[16];
#pragma unroll
    for (int t = 0; t < 16; ++t) {
        int cv = 256 + h * 64 + (t >> 2) * 16 + quad * 4 + (t & 3);
        av[t] = ABkv[cv];
        bv[t] = ABkv[768 + cv];
    }
#pragma unroll
    for (int j = 0; j < 5; ++j) {
        float l = lsum[j];
        l += __shfl_xor(l, 16);
        l += __shfl_xor(l, 32);
        float inv = 1.f / l;
        int qrow = b * 320 + j * 64 + wave * 16 + lc;
        u16* dst = o_act + (size_t)qrow * 512 + h * 64 + quad * 4;
#pragma unroll
        for (int nt = 0; nt < 4; ++nt) {
            ushort4 st;
#pragma unroll
            for (int r = 0; r < 4; ++r) {
                float o = av[nt * 4 + r] * (acc[j][nt][r] * inv) + bv[nt * 4 + r];
                float hs = o * fminf(fmaxf(o + 3.f, 0.f), 6.f) * (1.f / 6.f);
                ((u16*)&st)[r] = f2b(hs);
            }
            *(ushort4*)(dst + nt * 16) = st;
        }
    }
}

// ---------------- final BN apply -> d_out (fp32) ----------------
__global__ void bn_apply_out(const float* __restrict__ praw, const float* __restrict__ ABp,
                             float* __restrict__ out, int n4) {
    int i = blockIdx.x * 256 + threadIdx.x;
    if (i >= n4) return;
    int e = i << 2;
    int c = e & 511;
    float4 v = ((const float4*)praw)[i];
    float4 o;
    o.x = v.x * ABp[c]     + ABp[512 + c];
    o.y = v.y * ABp[c + 1] + ABp[512 + c + 1];
    o.z = v.z * ABp[c + 2] + ABp[512 + c + 2];
    o.w = v.w * ABp[c + 3] + ABp[512 + c + 3];
    ((float4*)out)[i] = o;
}

// ---------------- launcher ----------------
extern "C" void kernel_launch(void* const* d_in, const int* in_sizes, int n_in,
                              void* d_out, int out_size, void* d_ws, size_t ws_size,
                              hipStream_t stream) {
    const float* x   = (const float*)d_in[0];
    const float* Wkv = (const float*)d_in[1];
    const float* gkv = (const float*)d_in[2];
    const float* bkv = (const float*)d_in[3];
    const float* Wq  = (const float*)d_in[4];
    const float* gq  = (const float*)d_in[5];
    const float* bq  = (const float*)d_in[6];
    const float* Wp  = (const float*)d_in[7];
    const float* gp  = (const float*)d_in[8];
    const float* bp  = (const float*)d_in[9];
    float* out = (float*)d_out;

    char* ws = (char*)d_ws;
    size_t off = 0;
    auto alloc = [&](size_t bytes) -> void* {
        void* p = ws + off;
        off += (bytes + 255) & ~(size_t)255;
        return p;
    };
    // slot1: x_b (dead after gemm_kv/gather) -> p_raw (written by gemm_p after attn)
    void*  slot1  = alloc(81920ull * 256 * 2);                // 41.9 MB
    u16*   x_b    = (u16*)slot1;
    float* p_raw  = (float*)slot1;
    u16*   K_raw  = (u16*)alloc(81920ull * 256 * 2);          // 41.9 MB raw K, permuted rows
    u16*   Vt_raw = (u16*)alloc(512ull * 81920 * 2);          // 83.9 MB raw V^T [h*64+d][81920]
    u16*   q_raw  = (u16*)alloc(20480ull * 256 * 2);          // 10.5 MB
    // slot2: xsub (dead after gemm_q) -> o_act
    void*  slot2  = alloc(20480ull * 512 * 2);                // 21.0 MB
    u16*   xsub_b = (u16*)slot2;
    u16*   o_act  = (u16*)slot2;
    u16*   Wkv_b  = (u16*)alloc(768ull * 256 * 2);
    u16*   Wq_b   = (u16*)alloc(256ull * 256 * 2);
    u16*   Wp_b   = (u16*)alloc(512ull * 512 * 2);
    float* sums_kv = (float*)alloc(8 * 2 * 768 * sizeof(float));
    float* sums_q  = (float*)alloc(8 * 2 * 256 * sizeof(float));
    float* sums_p  = (float*)alloc(8 * 2 * 512 * sizeof(float));
    float* ABkv = (float*)alloc(1536 * sizeof(float));
    float* ABq  = (float*)alloc(512 * sizeof(float));
    float* ABp  = (float*)alloc(1024 * sizeof(float));

    dim3 blk(256);
    hipMemsetAsync(sums_kv, 0, 8 * 2 * (768 + 256 + 512) * sizeof(float), stream);

    convert_f32_bf16<<<20480, blk, 0, stream>>>(x,   x_b,   5242880);
    convert_wkv_perm<<<768,   blk, 0, stream>>>(Wkv, Wkv_b);
    convert_f32_bf16<<<64,    blk, 0, stream>>>(Wq,  Wq_b,  16384);
    convert_f32_bf16<<<256,   blk, 0, stream>>>(Wp,  Wp_b,  65536);
    gather_sub_bf16<<<2560,   blk, 0, stream>>>(x_b, xsub_b, 655360);

    // A-in-LDS GEMMs: grid = (M/128)*NT blocks of 256 threads, XCD-swizzled in-kernel
    gemm_ls<2, 6, 256><<<3840, blk, 0, stream>>>(x_b,    Wkv_b, K_raw, Vt_raw, 768, sums_kv);
    gemm_ls<0, 2, 256><<<320,  blk, 0, stream>>>(xsub_b, Wq_b,  q_raw, nullptr, 256, sums_q);

    finalize_bn<<<3, blk, 0, stream>>>(sums_kv, gkv, bkv, 768, 1.f / 81920.f, 1.f, ABkv, 1);
    finalize_bn<<<1, blk, 0, stream>>>(sums_q,  gq,  bq,  256, 1.f / 20480.f, SCALEF * LOG2E, ABq, 0);

    attn_kernel5<<<dim3(8, 64), blk, 0, stream>>>(K_raw, Vt_raw, q_raw, ABq, ABkv, o_act);

    gemm_ls<1, 4, 512><<<640, blk, 0, stream>>>(o_act, Wp_b, p_raw, nullptr, 512, sums_p);
    finalize_bn<<<2, blk, 0, stream>>>(sums_p, gp, bp, 512, 1.f / 20480.f, 1.f, ABp, 0);

    bn_apply_out<<<10240, blk, 0, stream>>>(p_raw, ABp, out, 2621440);
}

// Round 7
// 351.039 us; speedup vs baseline: 1.2281x; 1.0836x over previous
//
#include <hip/hip_runtime.h>
#include <hip/hip_bf16.h>
#include <math.h>

#define EPSF 1e-5f
#define SCALEF 0.17677669529663687f  // 32^-0.5
#define LOG2E 1.4426950408889634f

typedef unsigned short u16;
typedef unsigned int u32;
typedef __attribute__((ext_vector_type(8))) short bf16x8;
typedef __attribute__((ext_vector_type(4))) float f32x4;

__device__ __forceinline__ float b2f(u16 u) {
    union { unsigned int i; float f; } v; v.i = ((unsigned int)u) << 16; return v.f;
}
__device__ __forceinline__ u16 f2b(float f) {
    union { float f; unsigned int i; } v; v.f = f;
    unsigned int x = v.i;
    return (u16)((x + 0x7fffu + ((x >> 16) & 1u)) >> 16);  // RNE, finite inputs
}
__device__ __forceinline__ float fexp2(float x) {
#if __has_builtin(__builtin_amdgcn_exp2f)
    return __builtin_amdgcn_exp2f(x);
#else
    return exp2f(x);
#endif
}
__device__ __forceinline__ u32 cvtpk_bf16(float lo, float hi) {
    u32 r;
    asm("v_cvt_pk_bf16_f32 %0, %1, %2" : "=v"(r) : "v"(lo), "v"(hi));
    return r;
}
// async global->LDS, 16B per lane; LDS dest is wave-uniform base + lane*16
__device__ __forceinline__ void gload_lds16(const u16* __restrict__ g, u16* l) {
    __builtin_amdgcn_global_load_lds(
        (const __attribute__((address_space(1))) void*)g,
        (__attribute__((address_space(3))) void*)l, 16, 0, 0);
}

// ---------------- fp32 -> bf16 convert (vectorized x4) ----------------
__global__ void convert_f32_bf16(const float* __restrict__ src, u16* __restrict__ dst, int n4) {
    int i = blockIdx.x * 256 + threadIdx.x;
    if (i >= n4) return;
    float4 v = ((const float4*)src)[i];
    ushort4 o;
    o.x = f2b(v.x); o.y = f2b(v.y); o.z = f2b(v.z); o.w = f2b(v.w);
    ((ushort4*)dst)[i] = o;
}

// ---------------- W_kv row-permute + convert: K-channels first (256), then V (512) ----------------
__global__ void convert_wkv_perm(const float* __restrict__ W, u16* __restrict__ out) {
    int r = blockIdx.x, cl = threadIdx.x;
    int src = (r < 256) ? ((r >> 5) * 96 + (r & 31))
                        : (((r - 256) >> 6) * 96 + 32 + ((r - 256) & 63));
    out[r * 256 + cl] = f2b(W[src * 256 + cl]);
}

// ---------------- subsample gather (bf16 x_b -> bf16 x_sub) ----------------
__global__ void gather_sub_bf16(const u16* __restrict__ xb, u16* __restrict__ xsub, int n8) {
    int i = blockIdx.x * 256 + threadIdx.x;
    if (i >= n8) return;
    int e = i << 3;
    int row = e >> 8;
    int col = e & 255;
    int b = row / 320;
    int t = row - b * 320;
    int n;
    if (t < 256) n = ((t >> 4) << 6) + ((t & 15) << 1);
    else { int tt = t - 256; n = 1024 + ((tt >> 3) << 5) + ((tt & 7) << 1); }
    *(int4*)(xsub + e) = *(const int4*)(xb + ((size_t)(b * 1280 + n)) * 256 + col);
}

// ---------------- GEMM: C[M,N] = A[M,K](bf16) * W[N,K]^T(bf16), fused BN stats ----------------
// MERGE of the two measured-best components:
//  - loop: R3's single-buffered 2-barrier K-step (global_load_lds w16, vmcnt(0), 16 MFMA) — 78 µs
//  - grid: R6's in-kernel XCD swizzle (id&7 -> xcd, contiguous M-chunk/XCD, N fastest) — FETCH 125->22 MB,
//    so the per-iter vmcnt drain waits on L2 (~200cy) instead of HBM (~900cy) for A after first touch.
// MODE 0: bf16 C. MODE 1: f32 C. MODE 2 (KV, W pre-permuted K-first): n0<256 -> K_raw (attn's
// permuted key rows); else Vt_raw transposed [c'][81920] via cvt_pk (8B stores).
// Stats: per-channel sum/sumsq -> sumbuf -> atomicAdd sums[rep][2][N], rep = m_t&7.
template<int MODE, int NT>
__global__ __launch_bounds__(256) void gemm_bt(const u16* __restrict__ A, const u16* __restrict__ Bw,
                                               void* __restrict__ Cv, void* __restrict__ C2v,
                                               int N, int K, float* __restrict__ sums) {
    __shared__ u16 As[128 * 32];
    __shared__ u16 Bs[128 * 32];
    __shared__ float sumbuf[4][64][2];
    const int tid = threadIdx.x;
    const int wave = tid >> 6, lane = tid & 63;
    const int quad = lane >> 4, lc = lane & 15;
    const int wr = wave >> 1, wc = wave & 1;
    const int id = blockIdx.x;
    const int xcd = id & 7, l = id >> 3;
    const int mchunk = ((int)gridDim.x >> 3) / NT;
    const int m_t = xcd * mchunk + l / NT;
    const int n_t = l - (l / NT) * NT;
    const int m0 = m_t * 128, n0 = n_t * 128;

    // staging: wave w stages rows [32w,32w+32); one instr = 16 rows (lane i -> row i/4, col (i&3)*8)
    const int srow = (wave << 5) + (lane >> 2);
    const int scol = (lane & 3) << 3;
    u16* ldsA0 = As + ((wave << 5) + 0) * 32;
    u16* ldsA1 = As + ((wave << 5) + 16) * 32;
    u16* ldsB0 = Bs + ((wave << 5) + 0) * 32;
    u16* ldsB1 = Bs + ((wave << 5) + 16) * 32;
    const u16* gA0 = A  + (size_t)(m0 + srow) * K + scol;
    const u16* gA1 = A  + (size_t)(m0 + srow + 16) * K + scol;
    const u16* gB0 = Bw + (size_t)(n0 + srow) * K + scol;
    const u16* gB1 = Bw + (size_t)(n0 + srow + 16) * K + scol;

    f32x4 acc[4][4];
#pragma unroll
    for (int i = 0; i < 4; ++i)
#pragma unroll
        for (int j = 0; j < 4; ++j) acc[i][j] = (f32x4){0.f, 0.f, 0.f, 0.f};

    for (int k0 = 0; k0 < K; k0 += 32) {
        __syncthreads();
        gload_lds16(gA0 + k0, ldsA0);
        gload_lds16(gA1 + k0, ldsA1);
        gload_lds16(gB0 + k0, ldsB0);
        gload_lds16(gB1 + k0, ldsB1);
        asm volatile("s_waitcnt vmcnt(0)" ::: "memory");
        __syncthreads();
        bf16x8 af[4], bfr[4];
#pragma unroll
        for (int mi = 0; mi < 4; ++mi) af[mi]  = *(const bf16x8*)&As[(wr * 64 + mi * 16 + lc) * 32 + quad * 8];
#pragma unroll
        for (int ni = 0; ni < 4; ++ni) bfr[ni] = *(const bf16x8*)&Bs[(wc * 64 + ni * 16 + lc) * 32 + quad * 8];
#pragma unroll
        for (int mi = 0; mi < 4; ++mi)
#pragma unroll
            for (int ni = 0; ni < 4; ++ni)
                acc[mi][ni] = __builtin_amdgcn_mfma_f32_16x16x32_bf16(af[mi], bfr[ni], acc[mi][ni], 0, 0, 0);
    }

    // ---- per-channel stats (raw fp32 acc) ----
    float ps[4], ps2[4];
#pragma unroll
    for (int ni = 0; ni < 4; ++ni) { ps[ni] = 0.f; ps2[ni] = 0.f; }
#pragma unroll
    for (int mi = 0; mi < 4; ++mi)
#pragma unroll
        for (int ni = 0; ni < 4; ++ni)
#pragma unroll
            for (int r = 0; r < 4; ++r) {
                float v = acc[mi][ni][r];
                ps[ni] += v; ps2[ni] += v * v;
            }

    // ---- C write ----
    if (MODE == 0 || MODE == 1) {
#pragma unroll
        for (int mi = 0; mi < 4; ++mi)
#pragma unroll
            for (int ni = 0; ni < 4; ++ni)
#pragma unroll
                for (int r = 0; r < 4; ++r) {
                    int row = m0 + wr * 64 + mi * 16 + quad * 4 + r;
                    int cn  = n0 + wc * 64 + ni * 16 + lc;
                    float v = acc[mi][ni][r];
                    if (MODE == 1) ((float*)Cv)[(size_t)row * N + cn] = v;
                    else           ((u16*)Cv)[(size_t)row * N + cn] = f2b(v);
                }
    } else if (n0 < 256) {
        // K-block: raw bf16 at permuted key row [perm-token][256]
        u16* Kr = (u16*)Cv;
#pragma unroll
        for (int mi = 0; mi < 4; ++mi)
#pragma unroll
            for (int r = 0; r < 4; ++r) {
                int t = m0 + wr * 64 + mi * 16 + quad * 4 + r;
                int kk = t & 31;
                int pr = (t & ~31) + ((kk & 4) << 2) + ((kk >> 3) << 2) + (kk & 3);
#pragma unroll
                for (int ni = 0; ni < 4; ++ni) {
                    int c = n0 + wc * 64 + ni * 16 + lc;
                    Kr[(size_t)pr * 256 + c] = f2b(acc[mi][ni][r]);
                }
            }
    } else {
        // V-block: raw bf16 transposed [c'][81920], 4 consecutive tokens per 8B store
        u16* Vt = (u16*)C2v;
#pragma unroll
        for (int mi = 0; mi < 4; ++mi)
#pragma unroll
            for (int ni = 0; ni < 4; ++ni) {
                int cp = n0 - 256 + wc * 64 + ni * 16 + lc;
                int t0 = m0 + wr * 64 + mi * 16 + quad * 4;
                uint2 w;
                w.x = cvtpk_bf16(acc[mi][ni][0], acc[mi][ni][1]);
                w.y = cvtpk_bf16(acc[mi][ni][2], acc[mi][ni][3]);
                *(uint2*)(Vt + (size_t)cp * 81920 + t0) = w;
            }
    }

    // ---- cross-quad reduce + atomic ----
#pragma unroll
    for (int ni = 0; ni < 4; ++ni) {
        ps[ni]  += __shfl_xor(ps[ni], 16);  ps[ni]  += __shfl_xor(ps[ni], 32);
        ps2[ni] += __shfl_xor(ps2[ni], 16); ps2[ni] += __shfl_xor(ps2[ni], 32);
    }
    if (quad == 0) {
#pragma unroll
        for (int ni = 0; ni < 4; ++ni) {
            sumbuf[wave][ni * 16 + lc][0] = ps[ni];
            sumbuf[wave][ni * 16 + lc][1] = ps2[ni];
        }
    }
    __syncthreads();
    {
        int which = tid & 1, idx = (tid >> 1) & 63, wcg = tid >> 7;
        int channel = n0 + wcg * 64 + idx;
        float v = sumbuf[wcg][idx][which] + sumbuf[wcg + 2][idx][which];
        int rep = m_t & 7;
        atomicAdd(&sums[(rep * 2 + which) * N + channel], v);
    }
}

// ---------------- fold BN into per-channel affine (sums replicated x8) ----------------
__global__ void finalize_bn(const float* __restrict__ sum2, const float* __restrict__ g,
                            const float* __restrict__ beta, int cols, float inv_n, float scale,
                            float* __restrict__ AB, int kvperm) {
    int c = blockIdx.x * 256 + threadIdx.x;
    if (c >= cols) return;
    float s = 0.f, s2 = 0.f;
#pragma unroll
    for (int r = 0; r < 8; ++r) {
        s  += sum2[(r * 2 + 0) * cols + c];
        s2 += sum2[(r * 2 + 1) * cols + c];
    }
    int src = c;
    if (kvperm) {
        src = (c < 256) ? ((c >> 5) * 96 + (c & 31))
                        : (((c - 256) >> 6) * 96 + 32 + ((c - 256) & 63));
    }
    float m = s * inv_n;
    float var = s2 * inv_n - m * m;
    float a = g[src] * rsqrtf(var + EPSF) * scale;
    AB[c] = a;
    AB[cols + c] = beta[src] * scale - m * a;
}

// ---------------- fused attention v5: raw K/V, affines folded out of the loop ----------------
__global__ __launch_bounds__(256, 2) void attn_kernel5(const u16* __restrict__ Kr, const u16* __restrict__ Vt,
                                                       const u16* __restrict__ q_raw,
                                                       const float* __restrict__ ABq,
                                                       const float* __restrict__ ABkv,
                                                       u16* __restrict__ o_act) {
    const int tid = threadIdx.x;
    const int wave = tid >> 6, lane = tid & 63;
    const int quad = lane >> 4, lc = lane & 15;
    const int h = blockIdx.x, b = blockIdx.y;

    float qa[8], qb[8];
#pragma unroll
    for (int j = 0; j < 8; ++j) {
        int c = h * 32 + quad * 8 + j;
        float ak = ABkv[c];
        qa[j] = ABq[c] * ak;
        qb[j] = ABq[256 + c] * ak;
    }
    bf16x8 qf[5];
#pragma unroll
    for (int j = 0; j < 5; ++j) {
        const u16* qs = q_raw + ((size_t)(b * 320 + j * 64 + wave * 16 + lc)) * 256 + h * 32 + quad * 8;
        union { int4 v; u16 u[8]; } ld; ld.v = *(const int4*)qs;
        union { bf16x8 v; u16 u[8]; } st;
#pragma unroll
        for (int jj = 0; jj < 8; ++jj) st.u[jj] = f2b(b2f(ld.u[jj]) * qa[jj] + qb[jj]);
        qf[j] = st.v;
    }

    const u16* Kp = Kr + (size_t)b * 1280 * 256 + (size_t)lc * 256 + h * 32 + quad * 8;
    const u16* Vp = Vt + ((size_t)(h * 64 + lc)) * 81920 + b * 1280 + quad * 8;

    f32x4 acc[5][4];
#pragma unroll
    for (int j = 0; j < 5; ++j)
#pragma unroll
        for (int i = 0; i < 4; ++i) acc[j][i] = (f32x4){0.f, 0.f, 0.f, 0.f};
    float lsum[5];
#pragma unroll
    for (int j = 0; j < 5; ++j) lsum[j] = 0.f;

    const f32x4 z = (f32x4){0.f, 0.f, 0.f, 0.f};
    for (int kc = 0; kc < 1280; kc += 32) {
        bf16x8 kfA = *(const bf16x8*)(Kp + (size_t)kc * 256);
        bf16x8 kfB = *(const bf16x8*)(Kp + (size_t)(kc + 16) * 256);
        bf16x8 vf0 = *(const bf16x8*)(Vp + kc);
        bf16x8 vf1 = *(const bf16x8*)(Vp + (size_t)16 * 81920 + kc);
        bf16x8 vf2 = *(const bf16x8*)(Vp + (size_t)32 * 81920 + kc);
        bf16x8 vf3 = *(const bf16x8*)(Vp + (size_t)48 * 81920 + kc);
        f32x4 s0[5], s1[5];
#pragma unroll
        for (int j = 0; j < 5; ++j) {
            s0[j] = __builtin_amdgcn_mfma_f32_16x16x32_bf16(kfA, qf[j], z, 0, 0, 0);
            s1[j] = __builtin_amdgcn_mfma_f32_16x16x32_bf16(kfB, qf[j], z, 0, 0, 0);
        }
#pragma unroll
        for (int j = 0; j < 5; ++j) {
            float p0 = fexp2(s0[j][0]);
            float p1 = fexp2(s0[j][1]);
            float p2 = fexp2(s0[j][2]);
            float p3 = fexp2(s0[j][3]);
            float p4 = fexp2(s1[j][0]);
            float p5 = fexp2(s1[j][1]);
            float p6 = fexp2(s1[j][2]);
            float p7 = fexp2(s1[j][3]);
            lsum[j] += ((p0 + p1) + (p2 + p3)) + ((p4 + p5) + (p6 + p7));
            union { u32 w[4]; bf16x8 v; } pf;
            pf.w[0] = cvtpk_bf16(p0, p1);
            pf.w[1] = cvtpk_bf16(p2, p3);
            pf.w[2] = cvtpk_bf16(p4, p5);
            pf.w[3] = cvtpk_bf16(p6, p7);
            acc[j][0] = __builtin_amdgcn_mfma_f32_16x16x32_bf16(vf0, pf.v, acc[j][0], 0, 0, 0);
            acc[j][1] = __builtin_amdgcn_mfma_f32_16x16x32_bf16(vf1, pf.v, acc[j][1], 0, 0, 0);
            acc[j][2] = __builtin_amdgcn_mfma_f32_16x16x32_bf16(vf2, pf.v, acc[j][2], 0, 0, 0);
            acc[j][3] = __builtin_amdgcn_mfma_f32_16x16x32_bf16(vf3, pf.v, acc[j][3], 0, 0, 0);
        }
    }
    float av[16], bv[16];
#pragma unroll
    for (int t = 0; t < 16; ++t) {
        int cv = 256 + h * 64 + (t >> 2) * 16 + quad * 4 + (t & 3);
        av[t] = ABkv[cv];
        bv[t] = ABkv[768 + cv];
    }
#pragma unroll
    for (int j = 0; j < 5; ++j) {
        float l = lsum[j];
        l += __shfl_xor(l, 16);
        l += __shfl_xor(l, 32);
        float inv = 1.f / l;
        int qrow = b * 320 + j * 64 + wave * 16 + lc;
        u16* dst = o_act + (size_t)qrow * 512 + h * 64 + quad * 4;
#pragma unroll
        for (int nt = 0; nt < 4; ++nt) {
            ushort4 st;
#pragma unroll
            for (int r = 0; r < 4; ++r) {
                float o = av[nt * 4 + r] * (acc[j][nt][r] * inv) + bv[nt * 4 + r];
                float hs = o * fminf(fmaxf(o + 3.f, 0.f), 6.f) * (1.f / 6.f);
                ((u16*)&st)[r] = f2b(hs);
            }
            *(ushort4*)(dst + nt * 16) = st;
        }
    }
}

// ---------------- final BN apply -> d_out (fp32) ----------------
__global__ void bn_apply_out(const float* __restrict__ praw, const float* __restrict__ ABp,
                             float* __restrict__ out, int n4) {
    int i = blockIdx.x * 256 + threadIdx.x;
    if (i >= n4) return;
    int e = i << 2;
    int c = e & 511;
    float4 v = ((const float4*)praw)[i];
    float4 o;
    o.x = v.x * ABp[c]     + ABp[512 + c];
    o.y = v.y * ABp[c + 1] + ABp[512 + c + 1];
    o.z = v.z * ABp[c + 2] + ABp[512 + c + 2];
    o.w = v.w * ABp[c + 3] + ABp[512 + c + 3];
    ((float4*)out)[i] = o;
}

// ---------------- launcher ----------------
extern "C" void kernel_launch(void* const* d_in, const int* in_sizes, int n_in,
                              void* d_out, int out_size, void* d_ws, size_t ws_size,
                              hipStream_t stream) {
    const float* x   = (const float*)d_in[0];
    const float* Wkv = (const float*)d_in[1];
    const float* gkv = (const float*)d_in[2];
    const float* bkv = (const float*)d_in[3];
    const float* Wq  = (const float*)d_in[4];
    const float* gq  = (const float*)d_in[5];
    const float* bq  = (const float*)d_in[6];
    const float* Wp  = (const float*)d_in[7];
    const float* gp  = (const float*)d_in[8];
    const float* bp  = (const float*)d_in[9];
    float* out = (float*)d_out;

    char* ws = (char*)d_ws;
    size_t off = 0;
    auto alloc = [&](size_t bytes) -> void* {
        void* p = ws + off;
        off += (bytes + 255) & ~(size_t)255;
        return p;
    };
    // slot1: x_b (dead after gemm_kv/gather) -> p_raw (written by gemm_p after attn)
    void*  slot1  = alloc(81920ull * 256 * 2);                // 41.9 MB
    u16*   x_b    = (u16*)slot1;
    float* p_raw  = (float*)slot1;
    u16*   K_raw  = (u16*)alloc(81920ull * 256 * 2);          // 41.9 MB raw K, permuted rows
    u16*   Vt_raw = (u16*)alloc(512ull * 81920 * 2);          // 83.9 MB raw V^T [h*64+d][81920]
    u16*   q_raw  = (u16*)alloc(20480ull * 256 * 2);          // 10.5 MB
    // slot2: xsub (dead after gemm_q) -> o_act
    void*  slot2  = alloc(20480ull * 512 * 2);                // 21.0 MB
    u16*   xsub_b = (u16*)slot2;
    u16*   o_act  = (u16*)slot2;
    u16*   Wkv_b  = (u16*)alloc(768ull * 256 * 2);
    u16*   Wq_b   = (u16*)alloc(256ull * 256 * 2);
    u16*   Wp_b   = (u16*)alloc(512ull * 512 * 2);
    float* sums_kv = (float*)alloc(8 * 2 * 768 * sizeof(float));
    float* sums_q  = (float*)alloc(8 * 2 * 256 * sizeof(float));
    float* sums_p  = (float*)alloc(8 * 2 * 512 * sizeof(float));
    float* ABkv = (float*)alloc(1536 * sizeof(float));
    float* ABq  = (float*)alloc(512 * sizeof(float));
    float* ABp  = (float*)alloc(1024 * sizeof(float));

    dim3 blk(256);
    hipMemsetAsync(sums_kv, 0, 8 * 2 * (768 + 256 + 512) * sizeof(float), stream);

    convert_f32_bf16<<<20480, blk, 0, stream>>>(x,   x_b,   5242880);
    convert_wkv_perm<<<768,   blk, 0, stream>>>(Wkv, Wkv_b);
    convert_f32_bf16<<<64,    blk, 0, stream>>>(Wq,  Wq_b,  16384);
    convert_f32_bf16<<<256,   blk, 0, stream>>>(Wp,  Wp_b,  65536);
    gather_sub_bf16<<<2560,   blk, 0, stream>>>(x_b, xsub_b, 655360);

    // grids: linear, in-kernel XCD swizzle (blocks sharing an A-panel land on one XCD)
    gemm_bt<2, 6><<<3840, blk, 0, stream>>>(x_b,    Wkv_b, K_raw, Vt_raw, 768, 256, sums_kv);
    gemm_bt<0, 2><<<320,  blk, 0, stream>>>(xsub_b, Wq_b,  q_raw, nullptr, 256, 256, sums_q);

    finalize_bn<<<3, blk, 0, stream>>>(sums_kv, gkv, bkv, 768, 1.f / 81920.f, 1.f, ABkv, 1);
    finalize_bn<<<1, blk, 0, stream>>>(sums_q,  gq,  bq,  256, 1.f / 20480.f, SCALEF * LOG2E, ABq, 0);

    attn_kernel5<<<dim3(8, 64), blk, 0, stream>>>(K_raw, Vt_raw, q_raw, ABq, ABkv, o_act);

    gemm_bt<1, 4><<<640, blk, 0, stream>>>(o_act, Wp_b, p_raw, nullptr, 512, 512, sums_p);
    finalize_bn<<<2, blk, 0, stream>>>(sums_p, gp, bp, 512, 1.f / 20480.f, 1.f, ABp, 0);

    bn_apply_out<<<10240, blk, 0, stream>>>(p_raw, ABp, out, 2621440);
}

// Round 8
// 349.506 us; speedup vs baseline: 1.2335x; 1.0044x over previous
//
#include <hip/hip_runtime.h>
#include <hip/hip_bf16.h>
#include <math.h>

#define EPSF 1e-5f
#define SCALEF 0.17677669529663687f  // 32^-0.5
#define LOG2E 1.4426950408889634f

typedef unsigned short u16;
typedef unsigned int u32;
typedef __attribute__((ext_vector_type(8))) short bf16x8;
typedef __attribute__((ext_vector_type(4))) float f32x4;

__device__ __forceinline__ float b2f(u16 u) {
    union { unsigned int i; float f; } v; v.i = ((unsigned int)u) << 16; return v.f;
}
__device__ __forceinline__ u16 f2b(float f) {
    union { float f; unsigned int i; } v; v.f = f;
    unsigned int x = v.i;
    return (u16)((x + 0x7fffu + ((x >> 16) & 1u)) >> 16);  // RNE, finite inputs
}
__device__ __forceinline__ float fexp2(float x) {
#if __has_builtin(__builtin_amdgcn_exp2f)
    return __builtin_amdgcn_exp2f(x);
#else
    return exp2f(x);
#endif
}
__device__ __forceinline__ u32 cvtpk_bf16(float lo, float hi) {
    u32 r;
    asm("v_cvt_pk_bf16_f32 %0, %1, %2" : "=v"(r) : "v"(lo), "v"(hi));
    return r;
}
// async global->LDS, 16B per lane; LDS dest is wave-uniform base + lane*16
__device__ __forceinline__ void gload_lds16(const u16* __restrict__ g, u16* l) {
    __builtin_amdgcn_global_load_lds(
        (const __attribute__((address_space(1))) void*)g,
        (__attribute__((address_space(3))) void*)l, 16, 0, 0);
}

// ---------------- fp32 -> bf16 convert (vectorized x4) ----------------
__global__ void convert_f32_bf16(const float* __restrict__ src, u16* __restrict__ dst, int n4) {
    int i = blockIdx.x * 256 + threadIdx.x;
    if (i >= n4) return;
    float4 v = ((const float4*)src)[i];
    ushort4 o;
    o.x = f2b(v.x); o.y = f2b(v.y); o.z = f2b(v.z); o.w = f2b(v.w);
    ((ushort4*)dst)[i] = o;
}

// ---------------- W_kv row-permute + convert: K-channels first (256), then V (512) ----------------
__global__ void convert_wkv_perm(const float* __restrict__ W, u16* __restrict__ out) {
    int r = blockIdx.x, cl = threadIdx.x;
    int src = (r < 256) ? ((r >> 5) * 96 + (r & 31))
                        : (((r - 256) >> 6) * 96 + 32 + ((r - 256) & 63));
    out[r * 256 + cl] = f2b(W[src * 256 + cl]);
}

// ---------------- subsample gather (bf16 x_b -> bf16 x_sub) ----------------
__global__ void gather_sub_bf16(const u16* __restrict__ xb, u16* __restrict__ xsub, int n8) {
    int i = blockIdx.x * 256 + threadIdx.x;
    if (i >= n8) return;
    int e = i << 3;
    int row = e >> 8;
    int col = e & 255;
    int b = row / 320;
    int t = row - b * 320;
    int n;
    if (t < 256) n = ((t >> 4) << 6) + ((t & 15) << 1);
    else { int tt = t - 256; n = 1024 + ((tt >> 3) << 5) + ((tt & 7) << 1); }
    *(int4*)(xsub + e) = *(const int4*)(xb + ((size_t)(b * 1280 + n)) * 256 + col);
}

// ---------------- GEMM, wave-private zero-barrier: C[M,N] = A[M,K] * W[N,K]^T, fused BN stats ----
// block 256 = 4 INDEPENDENT waves (2x2 over a 128x128 tile), each wave owns a private 16 KB LDS
// region: double-buffered {A 64x32 | B 64x32}. Per K-step: STAGE(next buf, 8 global_load_lds) ->
// s_waitcnt vmcnt(8) (counted: current tile landed, next stays in flight) -> ds_read frags ->
// 16 MFMA. ZERO barriers in the kernel; waves self-pace (attn-kernel structure). WAR on buffer
// reuse is closed by program order: iter-t ds_reads lgkmcnt-complete before iter-t MFMAs issue,
// which precede iter-(t+1)'s STAGE.
// XCD swizzle (measured FETCH 125->22 MB): id&7 -> xcd, contiguous M-chunk per XCD, N fastest.
// MODE 0: bf16 C. MODE 1: f32 C. MODE 2 (KV, W pre-permuted K-first): n0<256 -> K_raw (attn's
// permuted key rows); else Vt_raw transposed [c'][81920] via cvt_pk (8B stores).
// Stats: per-channel sum/sumsq, cross-quad shfl, quad0 direct atomicAdd sums[rep][2][N], rep=m_t&7.
template<int MODE, int NT, int KC>
__global__ __launch_bounds__(256) void gemm_wp(const u16* __restrict__ A, const u16* __restrict__ Bw,
                                               void* __restrict__ Cv, void* __restrict__ C2v,
                                               int N, float* __restrict__ sums) {
    __shared__ u16 L[4 * 8192];   // 64 KB: wave w owns L[w*8192 .. +8192) = 2 bufs x {A 2048 | B 2048}
    const int tid = threadIdx.x;
    const int wave = tid >> 6, lane = tid & 63;
    const int quad = lane >> 4, lc = lane & 15;
    const int wr = wave >> 1, wc = wave & 1;
    const int id = blockIdx.x;
    const int xcd = id & 7, l = id >> 3;
    const int mchunk = ((int)gridDim.x >> 3) / NT;
    const int m_t = xcd * mchunk + l / NT;
    const int n_t = l - (l / NT) * NT;
    const int m0 = m_t * 128, n0 = n_t * 128;

    u16* Lw = &L[wave * 8192];
    const int srow = lane >> 2;          // 0..15
    const int scol = (lane & 3) << 3;    // 0,8,16,24
    const u16* gA = A  + (size_t)(m0 + wr * 64 + srow) * KC + scol;
    const u16* gB = Bw + (size_t)(n0 + wc * 64 + srow) * KC + scol;

    f32x4 acc[4][4];
#pragma unroll
    for (int i = 0; i < 4; ++i)
#pragma unroll
        for (int j = 0; j < 4; ++j) acc[i][j] = (f32x4){0.f, 0.f, 0.f, 0.f};

    auto STAGE = [&](int buf, int t) {
#pragma unroll
        for (int s = 0; s < 4; ++s) {
            gload_lds16(gA + (size_t)(s * 16) * KC + t * 32, Lw + buf * 4096 + s * 512);
            gload_lds16(gB + (size_t)(s * 16) * KC + t * 32, Lw + buf * 4096 + 2048 + s * 512);
        }
    };

    STAGE(0, 0);
#pragma unroll
    for (int t = 0; t < KC / 32; ++t) {
        const int buf = t & 1;
        if (t + 1 < KC / 32) {
            STAGE(buf ^ 1, t + 1);                           // 8 loads stay in flight
            asm volatile("s_waitcnt vmcnt(8)" ::: "memory"); // current tile's 8 landed
        } else {
            asm volatile("s_waitcnt vmcnt(0)" ::: "memory");
        }
        bf16x8 af[4], bfr[4];
#pragma unroll
        for (int mi = 0; mi < 4; ++mi) af[mi]  = *(const bf16x8*)&Lw[buf * 4096 + (mi * 16 + lc) * 32 + quad * 8];
#pragma unroll
        for (int ni = 0; ni < 4; ++ni) bfr[ni] = *(const bf16x8*)&Lw[buf * 4096 + 2048 + (ni * 16 + lc) * 32 + quad * 8];
#pragma unroll
        for (int mi = 0; mi < 4; ++mi)
#pragma unroll
            for (int ni = 0; ni < 4; ++ni)
                acc[mi][ni] = __builtin_amdgcn_mfma_f32_16x16x32_bf16(af[mi], bfr[ni], acc[mi][ni], 0, 0, 0);
    }

    // ---- per-channel stats (raw fp32 acc) ----
    float ps[4], ps2[4];
#pragma unroll
    for (int ni = 0; ni < 4; ++ni) { ps[ni] = 0.f; ps2[ni] = 0.f; }
#pragma unroll
    for (int mi = 0; mi < 4; ++mi)
#pragma unroll
        for (int ni = 0; ni < 4; ++ni)
#pragma unroll
            for (int r = 0; r < 4; ++r) {
                float v = acc[mi][ni][r];
                ps[ni] += v; ps2[ni] += v * v;
            }
#pragma unroll
    for (int ni = 0; ni < 4; ++ni) {
        ps[ni]  += __shfl_xor(ps[ni], 16);  ps[ni]  += __shfl_xor(ps[ni], 32);
        ps2[ni] += __shfl_xor(ps2[ni], 16); ps2[ni] += __shfl_xor(ps2[ni], 32);
    }
    if (quad == 0) {
        int rep = m_t & 7;
#pragma unroll
        for (int ni = 0; ni < 4; ++ni) {
            int c = n0 + wc * 64 + ni * 16 + lc;
            atomicAdd(&sums[(rep * 2 + 0) * N + c], ps[ni]);
            atomicAdd(&sums[(rep * 2 + 1) * N + c], ps2[ni]);
        }
    }

    // ---- C write ----
    if (MODE == 0 || MODE == 1) {
#pragma unroll
        for (int mi = 0; mi < 4; ++mi)
#pragma unroll
            for (int ni = 0; ni < 4; ++ni)
#pragma unroll
                for (int r = 0; r < 4; ++r) {
                    int row = m0 + wr * 64 + mi * 16 + quad * 4 + r;
                    int cn  = n0 + wc * 64 + ni * 16 + lc;
                    float v = acc[mi][ni][r];
                    if (MODE == 1) ((float*)Cv)[(size_t)row * N + cn] = v;
                    else           ((u16*)Cv)[(size_t)row * N + cn] = f2b(v);
                }
    } else if (n0 < 256) {
        // K-block: raw bf16 at permuted key row [perm-token][256]
        u16* Kr = (u16*)Cv;
#pragma unroll
        for (int mi = 0; mi < 4; ++mi)
#pragma unroll
            for (int r = 0; r < 4; ++r) {
                int t = m0 + wr * 64 + mi * 16 + quad * 4 + r;
                int kk = t & 31;
                int pr = (t & ~31) + ((kk & 4) << 2) + ((kk >> 3) << 2) + (kk & 3);
#pragma unroll
                for (int ni = 0; ni < 4; ++ni) {
                    int c = n0 + wc * 64 + ni * 16 + lc;
                    Kr[(size_t)pr * 256 + c] = f2b(acc[mi][ni][r]);
                }
            }
    } else {
        // V-block: raw bf16 transposed [c'][81920], 4 consecutive tokens per 8B store
        u16* Vt = (u16*)C2v;
#pragma unroll
        for (int mi = 0; mi < 4; ++mi)
#pragma unroll
            for (int ni = 0; ni < 4; ++ni) {
                int cp = n0 - 256 + wc * 64 + ni * 16 + lc;
                int t0 = m0 + wr * 64 + mi * 16 + quad * 4;
                uint2 w;
                w.x = cvtpk_bf16(acc[mi][ni][0], acc[mi][ni][1]);
                w.y = cvtpk_bf16(acc[mi][ni][2], acc[mi][ni][3]);
                *(uint2*)(Vt + (size_t)cp * 81920 + t0) = w;
            }
    }
}

// ---------------- fold BN into per-channel affine (sums replicated x8) ----------------
__global__ void finalize_bn(const float* __restrict__ sum2, const float* __restrict__ g,
                            const float* __restrict__ beta, int cols, float inv_n, float scale,
                            float* __restrict__ AB, int kvperm) {
    int c = blockIdx.x * 256 + threadIdx.x;
    if (c >= cols) return;
    float s = 0.f, s2 = 0.f;
#pragma unroll
    for (int r = 0; r < 8; ++r) {
        s  += sum2[(r * 2 + 0) * cols + c];
        s2 += sum2[(r * 2 + 1) * cols + c];
    }
    int src = c;
    if (kvperm) {
        src = (c < 256) ? ((c >> 5) * 96 + (c & 31))
                        : (((c - 256) >> 6) * 96 + 32 + ((c - 256) & 63));
    }
    float m = s * inv_n;
    float var = s2 * inv_n - m * m;
    float a = g[src] * rsqrtf(var + EPSF) * scale;
    AB[c] = a;
    AB[cols + c] = beta[src] * scale - m * a;
}

// ---------------- fused attention v5: raw K/V, affines folded out of the loop ----------------
__global__ __launch_bounds__(256, 2) void attn_kernel5(const u16* __restrict__ Kr, const u16* __restrict__ Vt,
                                                       const u16* __restrict__ q_raw,
                                                       const float* __restrict__ ABq,
                                                       const float* __restrict__ ABkv,
                                                       u16* __restrict__ o_act) {
    const int tid = threadIdx.x;
    const int wave = tid >> 6, lane = tid & 63;
    const int quad = lane >> 4, lc = lane & 15;
    const int h = blockIdx.x, b = blockIdx.y;

    float qa[8], qb[8];
#pragma unroll
    for (int j = 0; j < 8; ++j) {
        int c = h * 32 + quad * 8 + j;
        float ak = ABkv[c];
        qa[j] = ABq[c] * ak;
        qb[j] = ABq[256 + c] * ak;
    }
    bf16x8 qf[5];
#pragma unroll
    for (int j = 0; j < 5; ++j) {
        const u16* qs = q_raw + ((size_t)(b * 320 + j * 64 + wave * 16 + lc)) * 256 + h * 32 + quad * 8;
        union { int4 v; u16 u[8]; } ld; ld.v = *(const int4*)qs;
        union { bf16x8 v; u16 u[8]; } st;
#pragma unroll
        for (int jj = 0; jj < 8; ++jj) st.u[jj] = f2b(b2f(ld.u[jj]) * qa[jj] + qb[jj]);
        qf[j] = st.v;
    }

    const u16* Kp = Kr + (size_t)b * 1280 * 256 + (size_t)lc * 256 + h * 32 + quad * 8;
    const u16* Vp = Vt + ((size_t)(h * 64 + lc)) * 81920 + b * 1280 + quad * 8;

    f32x4 acc[5][4];
#pragma unroll
    for (int j = 0; j < 5; ++j)
#pragma unroll
        for (int i = 0; i < 4; ++i) acc[j][i] = (f32x4){0.f, 0.f, 0.f, 0.f};
    float lsum[5];
#pragma unroll
    for (int j = 0; j < 5; ++j) lsum[j] = 0.f;

    const f32x4 z = (f32x4){0.f, 0.f, 0.f, 0.f};
    for (int kc = 0; kc < 1280; kc += 32) {
        bf16x8 kfA = *(const bf16x8*)(Kp + (size_t)kc * 256);
        bf16x8 kfB = *(const bf16x8*)(Kp + (size_t)(kc + 16) * 256);
        bf16x8 vf0 = *(const bf16x8*)(Vp + kc);
        bf16x8 vf1 = *(const bf16x8*)(Vp + (size_t)16 * 81920 + kc);
        bf16x8 vf2 = *(const bf16x8*)(Vp + (size_t)32 * 81920 + kc);
        bf16x8 vf3 = *(const bf16x8*)(Vp + (size_t)48 * 81920 + kc);
        f32x4 s0[5], s1[5];
#pragma unroll
        for (int j = 0; j < 5; ++j) {
            s0[j] = __builtin_amdgcn_mfma_f32_16x16x32_bf16(kfA, qf[j], z, 0, 0, 0);
            s1[j] = __builtin_amdgcn_mfma_f32_16x16x32_bf16(kfB, qf[j], z, 0, 0, 0);
        }
#pragma unroll
        for (int j = 0; j < 5; ++j) {
            float p0 = fexp2(s0[j][0]);
            float p1 = fexp2(s0[j][1]);
            float p2 = fexp2(s0[j][2]);
            float p3 = fexp2(s0[j][3]);
            float p4 = fexp2(s1[j][0]);
            float p5 = fexp2(s1[j][1]);
            float p6 = fexp2(s1[j][2]);
            float p7 = fexp2(s1[j][3]);
            lsum[j] += ((p0 + p1) + (p2 + p3)) + ((p4 + p5) + (p6 + p7));
            union { u32 w[4]; bf16x8 v; } pf;
            pf.w[0] = cvtpk_bf16(p0, p1);
            pf.w[1] = cvtpk_bf16(p2, p3);
            pf.w[2] = cvtpk_bf16(p4, p5);
            pf.w[3] = cvtpk_bf16(p6, p7);
            acc[j][0] = __builtin_amdgcn_mfma_f32_16x16x32_bf16(vf0, pf.v, acc[j][0], 0, 0, 0);
            acc[j][1] = __builtin_amdgcn_mfma_f32_16x16x32_bf16(vf1, pf.v, acc[j][1], 0, 0, 0);
            acc[j][2] = __builtin_amdgcn_mfma_f32_16x16x32_bf16(vf2, pf.v, acc[j][2], 0, 0, 0);
            acc[j][3] = __builtin_amdgcn_mfma_f32_16x16x32_bf16(vf3, pf.v, acc[j][3], 0, 0, 0);
        }
    }
    float av[16], bv[16];
#pragma unroll
    for (int t = 0; t < 16; ++t) {
        int cv = 256 + h * 64 + (t >> 2) * 16 + quad * 4 + (t & 3);
        av[t] = ABkv[cv];
        bv[t] = ABkv[768 + cv];
    }
#pragma unroll
    for (int j = 0; j < 5; ++j) {
        float l = lsum[j];
        l += __shfl_xor(l, 16);
        l += __shfl_xor(l, 32);
        float inv = 1.f / l;
        int qrow = b * 320 + j * 64 + wave * 16 + lc;
        u16* dst = o_act + (size_t)qrow * 512 + h * 64 + quad * 4;
#pragma unroll
        for (int nt = 0; nt < 4; ++nt) {
            ushort4 st;
#pragma unroll
            for (int r = 0; r < 4; ++r) {
                float o = av[nt * 4 + r] * (acc[j][nt][r] * inv) + bv[nt * 4 + r];
                float hs = o * fminf(fmaxf(o + 3.f, 0.f), 6.f) * (1.f / 6.f);
                ((u16*)&st)[r] = f2b(hs);
            }
            *(ushort4*)(dst + nt * 16) = st;
        }
    }
}

// ---------------- final BN apply -> d_out (fp32) ----------------
__global__ void bn_apply_out(const float* __restrict__ praw, const float* __restrict__ ABp,
                             float* __restrict__ out, int n4) {
    int i = blockIdx.x * 256 + threadIdx.x;
    if (i >= n4) return;
    int e = i << 2;
    int c = e & 511;
    float4 v = ((const float4*)praw)[i];
    float4 o;
    o.x = v.x * ABp[c]     + ABp[512 + c];
    o.y = v.y * ABp[c + 1] + ABp[512 + c + 1];
    o.z = v.z * ABp[c + 2] + ABp[512 + c + 2];
    o.w = v.w * ABp[c + 3] + ABp[512 + c + 3];
    ((float4*)out)[i] = o;
}

// ---------------- launcher ----------------
extern "C" void kernel_launch(void* const* d_in, const int* in_sizes, int n_in,
                              void* d_out, int out_size, void* d_ws, size_t ws_size,
                              hipStream_t stream) {
    const float* x   = (const float*)d_in[0];
    const float* Wkv = (const float*)d_in[1];
    const float* gkv = (const float*)d_in[2];
    const float* bkv = (const float*)d_in[3];
    const float* Wq  = (const float*)d_in[4];
    const float* gq  = (const float*)d_in[5];
    const float* bq  = (const float*)d_in[6];
    const float* Wp  = (const float*)d_in[7];
    const float* gp  = (const float*)d_in[8];
    const float* bp  = (const float*)d_in[9];
    float* out = (float*)d_out;

    char* ws = (char*)d_ws;
    size_t off = 0;
    auto alloc = [&](size_t bytes) -> void* {
        void* p = ws + off;
        off += (bytes + 255) & ~(size_t)255;
        return p;
    };
    // slot1: x_b (dead after gemm_kv/gather) -> p_raw (written by gemm_p after attn)
    void*  slot1  = alloc(81920ull * 256 * 2);                // 41.9 MB
    u16*   x_b    = (u16*)slot1;
    float* p_raw  = (float*)slot1;
    u16*   K_raw  = (u16*)alloc(81920ull * 256 * 2);          // 41.9 MB raw K, permuted rows
    u16*   Vt_raw = (u16*)alloc(512ull * 81920 * 2);          // 83.9 MB raw V^T [h*64+d][81920]
    u16*   q_raw  = (u16*)alloc(20480ull * 256 * 2);          // 10.5 MB
    // slot2: xsub (dead after gemm_q) -> o_act
    void*  slot2  = alloc(20480ull * 512 * 2);                // 21.0 MB
    u16*   xsub_b = (u16*)slot2;
    u16*   o_act  = (u16*)slot2;
    u16*   Wkv_b  = (u16*)alloc(768ull * 256 * 2);
    u16*   Wq_b   = (u16*)alloc(256ull * 256 * 2);
    u16*   Wp_b   = (u16*)alloc(512ull * 512 * 2);
    float* sums_kv = (float*)alloc(8 * 2 * 768 * sizeof(float));
    float* sums_q  = (float*)alloc(8 * 2 * 256 * sizeof(float));
    float* sums_p  = (float*)alloc(8 * 2 * 512 * sizeof(float));
    float* ABkv = (float*)alloc(1536 * sizeof(float));
    float* ABq  = (float*)alloc(512 * sizeof(float));
    float* ABp  = (float*)alloc(1024 * sizeof(float));

    dim3 blk(256);
    hipMemsetAsync(sums_kv, 0, 8 * 2 * (768 + 256 + 512) * sizeof(float), stream);

    convert_f32_bf16<<<20480, blk, 0, stream>>>(x,   x_b,   5242880);
    convert_wkv_perm<<<768,   blk, 0, stream>>>(Wkv, Wkv_b);
    convert_f32_bf16<<<64,    blk, 0, stream>>>(Wq,  Wq_b,  16384);
    convert_f32_bf16<<<256,   blk, 0, stream>>>(Wp,  Wp_b,  65536);
    gather_sub_bf16<<<2560,   blk, 0, stream>>>(x_b, xsub_b, 655360);

    // wave-private zero-barrier GEMMs; grids divisible by 8*NT for the XCD swizzle
    gemm_wp<2, 6, 256><<<3840, blk, 0, stream>>>(x_b,    Wkv_b, K_raw, Vt_raw, 768, sums_kv);
    gemm_wp<0, 2, 256><<<320,  blk, 0, stream>>>(xsub_b, Wq_b,  q_raw, nullptr, 256, sums_q);

    finalize_bn<<<3, blk, 0, stream>>>(sums_kv, gkv, bkv, 768, 1.f / 81920.f, 1.f, ABkv, 1);
    finalize_bn<<<1, blk, 0, stream>>>(sums_q,  gq,  bq,  256, 1.f / 20480.f, SCALEF * LOG2E, ABq, 0);

    attn_kernel5<<<dim3(8, 64), blk, 0, stream>>>(K_raw, Vt_raw, q_raw, ABq, ABkv, o_act);

    gemm_wp<1, 4, 512><<<640, blk, 0, stream>>>(o_act, Wp_b, p_raw, nullptr, 512, sums_p);
    finalize_bn<<<2, blk, 0, stream>>>(sums_p, gp, bp, 512, 1.f / 20480.f, 1.f, ABp, 0);

    bn_apply_out<<<10240, blk, 0, stream>>>(p_raw, ABp, out, 2621440);
}